// Round 1
// baseline (384.496 us; speedup 1.0000x reference)
//
#include <hip/hip_runtime.h>
#include <hip/hip_bf16.h>

#define BB 32
#define CPD 64
#define TT 4096
#define INDIM 256
#define HH 128
#define WW 128
#define CH 64
#define WARM 64
#define NCHUNK (TT/CH)

__device__ __forceinline__ float tanh_fast(float x){
    float e = __expf(2.0f*x);           // overflow -> inf -> tanh=1; underflow -> 0 -> tanh=-1
    return 1.0f - 2.0f/(e + 1.0f);
}

// K1: M[c][h] = sum_i proj[c,i] * w_ih[h,i]   (64x128, K=256)
__global__ __launch_bounds__(256) void k_proj(const float* __restrict__ proj,
                                              const float* __restrict__ w_ih,
                                              float* __restrict__ M){
    int g = blockIdx.x*256 + threadIdx.x;      // 0..8191
    int c = g >> 7, h = g & 127;
    float acc = 0.f;
    #pragma unroll 8
    for (int i = 0; i < INDIM; i += 4){
        float4 p = *(const float4*)&proj[c*INDIM + i];
        float4 q = *(const float4*)&w_ih[h*INDIM + i];
        acc = fmaf(p.x, q.x, acc);
        acc = fmaf(p.y, q.y, acc);
        acc = fmaf(p.z, q.z, acc);
        acc = fmaf(p.w, q.w, acc);
    }
    M[g] = acc;
}

// K2: xw[b][t][h] = sum_c control[b][c][t] * M[c][h]
// block: 256 threads, handles 64 t-values for one batch. grid (T/64, B)
__global__ __launch_bounds__(256) void k_xw(const float* __restrict__ control,
                                            const float* __restrict__ M,
                                            float* __restrict__ xw){
    __shared__ float ct[CPD][64];      // 16 KB   [c][t]
    __shared__ float Ml[CPD][HH];      // 32 KB
    int b  = blockIdx.y;
    int t0 = blockIdx.x * 64;
    int tid = threadIdx.x;

    #pragma unroll
    for (int k = 0; k < 32; ++k){                 // stage M (8192 elems)
        int f = tid + k*256;
        ((float*)Ml)[f] = M[f];
    }
    #pragma unroll
    for (int k = 0; k < 16; ++k){                 // stage control tile (4096 elems)
        int f = tid + k*256;
        int c = f >> 6, t = f & 63;
        ct[c][t] = control[((size_t)b*CPD + c)*TT + t0 + t];
    }
    __syncthreads();

    int h  = tid & 127;
    int tq = tid >> 7;                            // 0..1 -> 32 t's each
    float acc[32];
    #pragma unroll
    for (int j = 0; j < 32; ++j) acc[j] = 0.f;

    for (int c = 0; c < CPD; ++c){
        float mv = Ml[c][h];                      // 2-way bank alias: free
        const float* cr = &ct[c][tq*32];          // uniform: broadcast
        #pragma unroll
        for (int j = 0; j < 32; j += 4){
            float4 c4 = *(const float4*)&cr[j];
            acc[j+0] = fmaf(mv, c4.x, acc[j+0]);
            acc[j+1] = fmaf(mv, c4.y, acc[j+1]);
            acc[j+2] = fmaf(mv, c4.z, acc[j+2]);
            acc[j+3] = fmaf(mv, c4.w, acc[j+3]);
        }
    }
    #pragma unroll
    for (int j = 0; j < 32; ++j){
        int t = t0 + tq*32 + j;
        xw[((size_t)b*TT + t)*HH + h] = acc[j];   // lanes h-consecutive: coalesced
    }
}

// K3: chunked scan. grid (NCHUNK, B), block 128. Thread i owns h[i] and W_hh row i in VGPRs.
__global__ __launch_bounds__(128) void k_scan(const float* __restrict__ xw,
                                              const float* __restrict__ w_hh,
                                              float* __restrict__ hs){
    __shared__ float hsm[2][HH];
    int b     = blockIdx.y;
    int chunk = blockIdx.x;
    int tout  = chunk * CH;
    int tstart = tout - WARM; if (tstart < 0) tstart = 0;
    int tend  = tout + CH;
    int i = threadIdx.x;

    float w[HH];
    #pragma unroll
    for (int j = 0; j < HH; j += 4){
        float4 w4 = *(const float4*)&w_hh[i*HH + j];
        w[j] = w4.x; w[j+1] = w4.y; w[j+2] = w4.z; w[j+3] = w4.w;
    }

    hsm[0][i] = 0.f;
    hsm[1][i] = 0.f;
    __syncthreads();

    size_t base = (size_t)b*TT*HH + i;
    float xnext = xw[base + (size_t)tstart*HH];
    int p = 0;                                    // read buffer
    for (int t = tstart; t < tend; ++t){
        float x = xnext;
        int tn = (t+1 < TT) ? (t+1) : t;
        xnext = xw[base + (size_t)tn*HH];         // prefetch next step

        float a0 = 0.f, a1 = 0.f, a2 = 0.f, a3 = 0.f;
        const float* hb = hsm[p];
        #pragma unroll
        for (int j = 0; j < HH; j += 4){
            float4 h4 = *(const float4*)&hb[j];   // uniform addr: LDS broadcast
            a0 = fmaf(w[j+0], h4.x, a0);
            a1 = fmaf(w[j+1], h4.y, a1);
            a2 = fmaf(w[j+2], h4.z, a2);
            a3 = fmaf(w[j+3], h4.w, a3);
        }
        float nh = tanh_fast(x + ((a0+a1)+(a2+a3)));
        hsm[p^1][i] = nh;
        __syncthreads();                          // one barrier/step (double-buffered h)
        p ^= 1;
        if (t >= tout) hs[base + (size_t)t*HH] = nh;
    }
}

// K4: out[b][t][w] = sin( sum_k hs[b][t][k] * w_out[w][k] ), in place over the hs buffer (d_out).
// block: 256 threads, 64 t-rows. grid (T/64, B)
__global__ __launch_bounds__(256) void k_out(float* data,                      // hs in, out written in place
                                             const float* __restrict__ w_out){
    __shared__ float hsT[HH][68];      // [k][t], padded to 68 for 16B-aligned f4 reads (~35 KB)
    __shared__ float wo[WW][HH+1];     // padded 129: conflict-free spread reads (~66 KB)
    int b  = blockIdx.y;
    int t0 = blockIdx.x * 64;
    int tid = threadIdx.x;

    #pragma unroll
    for (int k = 0; k < 64; ++k){                 // stage w_out (16384 elems)
        int f = tid + k*256;
        wo[f >> 7][f & 127] = w_out[f];
    }
    size_t rowbase = ((size_t)b*TT + t0)*HH;
    #pragma unroll
    for (int k = 0; k < 32; ++k){                 // stage hs tile transposed (8192 elems)
        int f = tid + k*256;
        int t = f >> 7, kk = f & 127;
        hsT[kk][t] = data[rowbase + f];
    }
    __syncthreads();

    int w_ = tid & 127;
    int tq = tid >> 7;
    float acc[32];
    #pragma unroll
    for (int j = 0; j < 32; ++j) acc[j] = 0.f;

    for (int k = 0; k < HH; ++k){
        float wv = wo[w_][k];                     // (w_+k)%32 spread: free
        const float* hr = &hsT[k][tq*32];         // uniform: broadcast
        #pragma unroll
        for (int j = 0; j < 32; j += 4){
            float4 h4 = *(const float4*)&hr[j];
            acc[j+0] = fmaf(wv, h4.x, acc[j+0]);
            acc[j+1] = fmaf(wv, h4.y, acc[j+1]);
            acc[j+2] = fmaf(wv, h4.z, acc[j+2]);
            acc[j+3] = fmaf(wv, h4.w, acc[j+3]);
        }
    }
    #pragma unroll
    for (int j = 0; j < 32; ++j){
        int t = t0 + tq*32 + j;
        data[((size_t)b*TT + t)*WW + w_] = __sinf(acc[j]);  // coalesced over w_
    }
}

extern "C" void kernel_launch(void* const* d_in, const int* in_sizes, int n_in,
                              void* d_out, int out_size, void* d_ws, size_t ws_size,
                              hipStream_t stream) {
    const float* control = (const float*)d_in[0];
    const float* proj    = (const float*)d_in[1];
    const float* w_ih    = (const float*)d_in[2];
    const float* w_hh    = (const float*)d_in[3];
    const float* w_out   = (const float*)d_in[4];

    float* M  = (float*)d_ws;                                  // 32 KB
    float* xw = (float*)((char*)d_ws + 65536);                 // 64 MB
    float* hs = (float*)d_out;                                 // hs lives in d_out (same size)

    k_proj<<<dim3(32), dim3(256), 0, stream>>>(proj, w_ih, M);
    k_xw  <<<dim3(TT/64, BB), dim3(256), 0, stream>>>(control, M, xw);
    k_scan<<<dim3(NCHUNK, BB), dim3(128), 0, stream>>>(xw, w_hh, hs);
    k_out <<<dim3(TT/64, BB), dim3(256), 0, stream>>>((float*)d_out, w_out);
}

// Round 2
// 315.249 us; speedup vs baseline: 1.2197x; 1.2197x over previous
//
#include <hip/hip_runtime.h>
#include <hip/hip_bf16.h>

#define BB 32
#define CPD 64
#define TT 4096
#define INDIM 256
#define HH 128
#define WW 128
#define CH 64
#define WARM 32
#define NB 2
#define NCHUNK (TT/CH)

__device__ __forceinline__ float tanh_fast(float x){
    float e = __expf(2.0f*x);           // overflow -> inf -> tanh=1; underflow -> 0 -> tanh=-1
    return 1.0f - 2.0f/(e + 1.0f);
}

// K1: M[c][h] = sum_i proj[c,i] * w_ih[h,i]   (64x128, K=256)
__global__ __launch_bounds__(256) void k_proj(const float* __restrict__ proj,
                                              const float* __restrict__ w_ih,
                                              float* __restrict__ M){
    int g = blockIdx.x*256 + threadIdx.x;      // 0..8191
    int c = g >> 7, h = g & 127;
    float acc = 0.f;
    #pragma unroll 8
    for (int i = 0; i < INDIM; i += 4){
        float4 p = *(const float4*)&proj[c*INDIM + i];
        float4 q = *(const float4*)&w_ih[h*INDIM + i];
        acc = fmaf(p.x, q.x, acc);
        acc = fmaf(p.y, q.y, acc);
        acc = fmaf(p.z, q.z, acc);
        acc = fmaf(p.w, q.w, acc);
    }
    M[g] = acc;
}

// K2: xw[b][t][h] = sum_c control[b][c][t] * M[c][h]
// block: 256 threads, handles 64 t-values for one batch. grid (T/64, B)
__global__ __launch_bounds__(256) void k_xw(const float* __restrict__ control,
                                            const float* __restrict__ M,
                                            float* __restrict__ xw){
    __shared__ float ct[CPD][64];      // 16 KB   [c][t]
    __shared__ float Ml[CPD][HH];      // 32 KB
    int b  = blockIdx.y;
    int t0 = blockIdx.x * 64;
    int tid = threadIdx.x;

    #pragma unroll
    for (int k = 0; k < 32; ++k){                 // stage M (8192 elems)
        int f = tid + k*256;
        ((float*)Ml)[f] = M[f];
    }
    #pragma unroll
    for (int k = 0; k < 16; ++k){                 // stage control tile (4096 elems)
        int f = tid + k*256;
        int c = f >> 6, t = f & 63;
        ct[c][t] = control[((size_t)b*CPD + c)*TT + t0 + t];
    }
    __syncthreads();

    int h  = tid & 127;
    int tq = tid >> 7;                            // 0..1 -> 32 t's each
    float acc[32];
    #pragma unroll
    for (int j = 0; j < 32; ++j) acc[j] = 0.f;

    for (int c = 0; c < CPD; ++c){
        float mv = Ml[c][h];                      // 2-way bank alias: free
        const float* cr = &ct[c][tq*32];          // uniform: broadcast
        #pragma unroll
        for (int j = 0; j < 32; j += 4){
            float4 c4 = *(const float4*)&cr[j];
            acc[j+0] = fmaf(mv, c4.x, acc[j+0]);
            acc[j+1] = fmaf(mv, c4.y, acc[j+1]);
            acc[j+2] = fmaf(mv, c4.z, acc[j+2]);
            acc[j+3] = fmaf(mv, c4.w, acc[j+3]);
        }
    }
    #pragma unroll
    for (int j = 0; j < 32; ++j){
        int t = t0 + tq*32 + j;
        xw[((size_t)b*TT + t)*HH + h] = acc[j];   // lanes h-consecutive: coalesced
    }
}

// K3: chunked scan, NB batches per block. grid (NCHUNK, B/NB), block 128.
// Thread i owns h-row i: W_hh row i pinned in 128 VGPRs, NB dot products/step.
__global__ __launch_bounds__(128, 1) void k_scan(const float* __restrict__ xw,
                                                 const float* __restrict__ w_hh,
                                                 float* __restrict__ hs){
    __shared__ float hsm[2][NB][HH];
    int b0    = blockIdx.y * NB;
    int chunk = blockIdx.x;
    int tout  = chunk * CH;
    int tstart = tout - WARM; if (tstart < 0) tstart = 0;
    int tend  = tout + CH;
    int i = threadIdx.x;

    float w[HH];
    #pragma unroll
    for (int j = 0; j < HH; j += 4){
        float4 w4 = *(const float4*)&w_hh[i*HH + j];
        w[j] = w4.x; w[j+1] = w4.y; w[j+2] = w4.z; w[j+3] = w4.w;
    }
    // pin w in VGPRs: opaque to the allocator's rematerialize-from-memory heuristic
    #pragma unroll
    for (int j = 0; j < HH; ++j) asm volatile("" : "+v"(w[j]));

    hsm[0][0][i] = 0.f;
    hsm[0][1][i] = 0.f;
    __syncthreads();

    size_t base0 = ((size_t)(b0+0)*TT)*HH + i;
    size_t base1 = ((size_t)(b0+1)*TT)*HH + i;
    float xn0 = xw[base0 + (size_t)tstart*HH];
    float xn1 = xw[base1 + (size_t)tstart*HH];
    int p = 0;                                    // read buffer
    for (int t = tstart; t < tend; ++t){
        float x0 = xn0, x1 = xn1;
        int tn = (t+1 < TT) ? (t+1) : t;
        xn0 = xw[base0 + (size_t)tn*HH];          // prefetch next step
        xn1 = xw[base1 + (size_t)tn*HH];

        float a00=0.f,a01=0.f,a02=0.f,a03=0.f;
        float a10=0.f,a11=0.f,a12=0.f,a13=0.f;
        const float* h0b = &hsm[p][0][0];
        const float* h1b = &hsm[p][1][0];
        #pragma unroll
        for (int j = 0; j < HH; j += 4){
            float4 h0 = *(const float4*)&h0b[j];  // uniform addr: LDS broadcast
            float4 h1 = *(const float4*)&h1b[j];
            a00 = fmaf(w[j+0], h0.x, a00);
            a01 = fmaf(w[j+1], h0.y, a01);
            a02 = fmaf(w[j+2], h0.z, a02);
            a03 = fmaf(w[j+3], h0.w, a03);
            a10 = fmaf(w[j+0], h1.x, a10);
            a11 = fmaf(w[j+1], h1.y, a11);
            a12 = fmaf(w[j+2], h1.z, a12);
            a13 = fmaf(w[j+3], h1.w, a13);
        }
        float nh0 = tanh_fast(x0 + ((a00+a01)+(a02+a03)));
        float nh1 = tanh_fast(x1 + ((a10+a11)+(a12+a13)));
        hsm[p^1][0][i] = nh0;
        hsm[p^1][1][i] = nh1;
        __syncthreads();                          // one barrier/step (double-buffered h)
        p ^= 1;
        if (t >= tout){
            hs[base0 + (size_t)t*HH] = nh0;
            hs[base1 + (size_t)t*HH] = nh1;
        }
    }
}

// K4: out[b][t][w] = sin( sum_k hs[b][t][k] * w_out[w][k] ), in place over the hs buffer (d_out).
// block: 256 threads, 64 t-rows. grid (T/64, B)
__global__ __launch_bounds__(256) void k_out(float* data,                      // hs in, out written in place
                                             const float* __restrict__ w_out){
    __shared__ float hsT[HH][68];      // [k][t], padded to 68 for 16B-aligned f4 reads (~35 KB)
    __shared__ float wo[WW][HH+1];     // padded 129: conflict-free spread reads (~66 KB)
    int b  = blockIdx.y;
    int t0 = blockIdx.x * 64;
    int tid = threadIdx.x;

    #pragma unroll
    for (int k = 0; k < 64; ++k){                 // stage w_out (16384 elems)
        int f = tid + k*256;
        wo[f >> 7][f & 127] = w_out[f];
    }
    size_t rowbase = ((size_t)b*TT + t0)*HH;
    #pragma unroll
    for (int k = 0; k < 32; ++k){                 // stage hs tile transposed (8192 elems)
        int f = tid + k*256;
        int t = f >> 7, kk = f & 127;
        hsT[kk][t] = data[rowbase + f];
    }
    __syncthreads();

    int w_ = tid & 127;
    int tq = tid >> 7;
    float acc[32];
    #pragma unroll
    for (int j = 0; j < 32; ++j) acc[j] = 0.f;

    for (int k = 0; k < HH; ++k){
        float wv = wo[w_][k];                     // (w_+k)%32 spread: free
        const float* hr = &hsT[k][tq*32];         // uniform: broadcast
        #pragma unroll
        for (int j = 0; j < 32; j += 4){
            float4 h4 = *(const float4*)&hr[j];
            acc[j+0] = fmaf(wv, h4.x, acc[j+0]);
            acc[j+1] = fmaf(wv, h4.y, acc[j+1]);
            acc[j+2] = fmaf(wv, h4.z, acc[j+2]);
            acc[j+3] = fmaf(wv, h4.w, acc[j+3]);
        }
    }
    #pragma unroll
    for (int j = 0; j < 32; ++j){
        int t = t0 + tq*32 + j;
        data[((size_t)b*TT + t)*WW + w_] = __sinf(acc[j]);  // coalesced over w_
    }
}

extern "C" void kernel_launch(void* const* d_in, const int* in_sizes, int n_in,
                              void* d_out, int out_size, void* d_ws, size_t ws_size,
                              hipStream_t stream) {
    const float* control = (const float*)d_in[0];
    const float* proj    = (const float*)d_in[1];
    const float* w_ih    = (const float*)d_in[2];
    const float* w_hh    = (const float*)d_in[3];
    const float* w_out   = (const float*)d_in[4];

    float* M  = (float*)d_ws;                                  // 32 KB
    float* xw = (float*)((char*)d_ws + 65536);                 // 64 MB
    float* hs = (float*)d_out;                                 // hs lives in d_out (same size)

    k_proj<<<dim3(32), dim3(256), 0, stream>>>(proj, w_ih, M);
    k_xw  <<<dim3(TT/64, BB), dim3(256), 0, stream>>>(control, M, xw);
    k_scan<<<dim3(NCHUNK, BB/NB), dim3(128), 0, stream>>>(xw, w_hh, hs);
    k_out <<<dim3(TT/64, BB), dim3(256), 0, stream>>>((float*)d_out, w_out);
}